// Round 15
// baseline (50.871 us; speedup 1.0000x reference)
//
#include <hip/hip_runtime.h>
#include <math.h>

#define T_LEN 24000
#define NCH   64
#define NSEQ  16       // BATCH * 2 directions
#define LCH   192      // chunk length
#define KCH   125      // KCH*LCH == T_LEN
#define NBLK  (NSEQ * KCH)
#define KB2   25       // P2 register batch
#define NXCD  8

static_assert(KCH * LCH == T_LEN, "chunking must cover T");

// Host-computed constants, passed by value (kernarg): 7 x 64 x 8 = 3584 B.
struct Coeffs {
    double a1[NCH], a2[NCH], b0[NCH];
    double A00[NCH], A01[NCH], A10[NCH], A11[NCH];  // A = M^LCH (entry->end)
};

// ws layout: stEnd double2[ST_D2] ; stEntry double2[ST_D2]
#define ST_D2     ((size_t)NSEQ * NCH * KCH)               // 128000
#define WS_FULL   (2 * ST_D2 * sizeof(double2))            // 4,096,000 B
#define WS_MID    (ST_D2 * sizeof(double2))                // 2,048,000 B

// XCD-aware swizzle (bijective: NBLK % 8 == 0).
__device__ __forceinline__ int swz(int b) {
    return (b % NXCD) * (NBLK / NXCD) + b / NXCD;
}

// ---- kernel A: zero-entry chunk end states --------------------------------
__global__ __launch_bounds__(64) void iir_endstates(
        const float* __restrict__ x, const Coeffs cf,
        double2* __restrict__ stEnd) {
    __shared__ float xs[LCH];
    const int g = swz(blockIdx.x), k = g % KCH, s = g / KCH;
    const int bi = s >> 1, dir = s & 1, c = threadIdx.x;
    const double a1 = cf.a1[c], a2 = cf.a2[c], b0 = cf.b0[c];
    const float* xb = x + (size_t)bi * T_LEN;
    const int t0 = k * LCH;
    #pragma unroll
    for (int w = 0; w < LCH / 64; ++w) {
        const int t = t0 + w * 64 + c;
        xs[w * 64 + c] = (dir == 0) ? xb[t] : xb[T_LEN - 1 - t];
    }
    __syncthreads();
    double y1 = 0.0, y2 = 0.0;
    #pragma unroll 16
    for (int j = 0; j < LCH; ++j) {
        // y1->y critical path is a single fp64 fma (y2 known 2 steps early)
        double y = fma(-a1, y1, fma(-a2, y2, b0 * (double)xs[j]));
        y2 = y1; y1 = y;
    }
    stEnd[((size_t)s * KCH + k) * NCH + c] = make_double2(y1, y2);
}

// ---- kernel P2: per-sequence entry-state scan (16 blocks) -----------------
__global__ __launch_bounds__(64) void iir_entries(
        const Coeffs cf, const double2* __restrict__ stEnd,
        double2* __restrict__ stEntry) {
    const int s = blockIdx.x, c = threadIdx.x;
    const double A00 = cf.A00[c], A01 = cf.A01[c];
    const double A10 = cf.A10[c], A11 = cf.A11[c];
    const double2* __restrict__ src = stEnd + (size_t)s * KCH * NCH;
    double2* __restrict__ dst = stEntry + (size_t)s * KCH * NCH;
    double in1 = 0.0, in2 = 0.0;
    for (int kb = 0; kb < KCH; kb += KB2) {
        double2 e[KB2];
        #pragma unroll
        for (int j = 0; j < KB2; ++j)
            e[j] = src[(size_t)(kb + j) * NCH + c];   // static idx -> VGPRs
        #pragma unroll
        for (int j = 0; j < KB2; ++j) {
            dst[(size_t)(kb + j) * NCH + c] = make_double2(in1, in2);
            const double n1 = e[j].x + fma(A00, in1, A01 * in2);
            const double n2 = e[j].y + fma(A10, in1, A11 * in2);
            in1 = n1; in2 = n2;
        }
    }
}

// ---- kernel B: barrier-free output ----------------------------------------
// Each thread owns one channel row. Register-buffer 32 consecutive y's
// (8 float4 = ONE full 128-B line of this row; rows are 128B-aligned since
// 24000*4 % 128 == 0), then 8 back-to-back dwordx4 stores fill the line.
// NO barriers after the x-stage -> no vmcnt(0) drain-lockstep; stores retire
// asynchronously under the continuing recursion.
__global__ __launch_bounds__(64) void iir_output(
        const float* __restrict__ x, const Coeffs cf,
        const double2* __restrict__ stEntry, float* __restrict__ out) {
    __shared__ float xs[LCH];
    const int g = swz(blockIdx.x), k = g % KCH, s = g / KCH;
    const int bi = s >> 1, dir = s & 1, c = threadIdx.x;
    const double a1 = cf.a1[c], a2 = cf.a2[c], b0 = cf.b0[c];
    const double2 ent = stEntry[((size_t)s * KCH + k) * NCH + c];
    const float* xb = x + (size_t)bi * T_LEN;
    const int t0 = k * LCH;
    #pragma unroll
    for (int w = 0; w < LCH / 64; ++w) {
        const int t = t0 + w * 64 + c;
        xs[w * 64 + c] = (dir == 0) ? xb[t] : xb[T_LEN - 1 - t];
    }
    __syncthreads();   // the only barrier: xs ready
    double y1 = ent.x, y2 = ent.y;
    float* __restrict__ rowp =
        out + (size_t)(bi * 128 + (dir ? 64 : 0) + c) * T_LEN;
    if (dir == 0) {
        for (int w = 0; w < LCH / 32; ++w) {
            float4 fb[8];
            #pragma unroll
            for (int jj = 0; jj < 32; ++jj) {        // slot == jj (static)
                double y = fma(-a1, y1,
                               fma(-a2, y2, b0 * (double)xs[w * 32 + jj]));
                y2 = y1; y1 = y;
                (&fb[jj >> 2].x)[jj & 3] = (float)y;
            }
            const int cb = t0 + w * 32;
            #pragma unroll
            for (int i = 0; i < 8; ++i)
                *(float4*)&rowp[cb + 4 * i] = fb[i];
        }
    } else {
        for (int w = 0; w < LCH / 32; ++w) {
            float4 fb[8];
            #pragma unroll
            for (int jj = 0; jj < 32; ++jj) {        // slot == 31-jj (static)
                double y = fma(-a1, y1,
                               fma(-a2, y2, b0 * (double)xs[w * 32 + jj]));
                y2 = y1; y1 = y;
                (&fb[(31 - jj) >> 2].x)[(31 - jj) & 3] = (float)y;
            }
            const int cb = T_LEN - 32 - t0 - w * 32;
            #pragma unroll
            for (int i = 0; i < 8; ++i)
                *(float4*)&rowp[cb + 4 * i] = fb[i];
        }
    }
}

// ---- mid tier: 2-kernel path (in-block scan + same barrier-free store) ----
__global__ __launch_bounds__(64) void iir_output_scan(
        const float* __restrict__ x, const Coeffs cf,
        const double2* __restrict__ stEnd, float* __restrict__ out) {
    __shared__ float xs[LCH];
    const int g = swz(blockIdx.x), k = g % KCH, s = g / KCH;
    const int bi = s >> 1, dir = s & 1, c = threadIdx.x;
    const double a1  = cf.a1[c],  a2  = cf.a2[c],  b0 = cf.b0[c];
    const double A00 = cf.A00[c], A01 = cf.A01[c];
    const double A10 = cf.A10[c], A11 = cf.A11[c];
    const float* xb = x + (size_t)bi * T_LEN;
    const int t0 = k * LCH;
    #pragma unroll
    for (int w = 0; w < LCH / 64; ++w) {
        const int t = t0 + w * 64 + c;
        xs[w * 64 + c] = (dir == 0) ? xb[t] : xb[T_LEN - 1 - t];
    }
    const double2* __restrict__ src = stEnd + (size_t)s * KCH * NCH;
    double in1 = 0.0, in2 = 0.0;
    #pragma unroll 8
    for (int j = 0; j < k; ++j) {
        const double2 e = src[(size_t)j * NCH + c];
        const double n1 = e.x + fma(A00, in1, A01 * in2);
        const double n2 = e.y + fma(A10, in1, A11 * in2);
        in1 = n1; in2 = n2;
    }
    __syncthreads();
    double y1 = in1, y2 = in2;
    float* __restrict__ rowp =
        out + (size_t)(bi * 128 + (dir ? 64 : 0) + c) * T_LEN;
    if (dir == 0) {
        for (int w = 0; w < LCH / 32; ++w) {
            float4 fb[8];
            #pragma unroll
            for (int jj = 0; jj < 32; ++jj) {
                double y = fma(-a1, y1,
                               fma(-a2, y2, b0 * (double)xs[w * 32 + jj]));
                y2 = y1; y1 = y;
                (&fb[jj >> 2].x)[jj & 3] = (float)y;
            }
            const int cb = t0 + w * 32;
            #pragma unroll
            for (int i = 0; i < 8; ++i)
                *(float4*)&rowp[cb + 4 * i] = fb[i];
        }
    } else {
        for (int w = 0; w < LCH / 32; ++w) {
            float4 fb[8];
            #pragma unroll
            for (int jj = 0; jj < 32; ++jj) {
                double y = fma(-a1, y1,
                               fma(-a2, y2, b0 * (double)xs[w * 32 + jj]));
                y2 = y1; y1 = y;
                (&fb[(31 - jj) >> 2].x)[(31 - jj) & 3] = (float)y;
            }
            const int cb = T_LEN - 32 - t0 - w * 32;
            #pragma unroll
            for (int i = 0; i < 8; ++i)
                *(float4*)&rowp[cb + 4 * i] = fb[i];
        }
    }
}

// ---- last-resort tier (no ws) ---------------------------------------------
__global__ __launch_bounds__(64) void iir_direct(
        const float* __restrict__ x, const Coeffs cf,
        float* __restrict__ out) {
    const int s = blockIdx.x, bi = s >> 1, dir = s & 1, c = threadIdx.x;
    const double a1 = cf.a1[c], a2 = cf.a2[c], b0 = cf.b0[c];
    const float* xb = x + (size_t)bi * T_LEN;
    float* __restrict__ rowp =
        out + (size_t)(bi * 128 + (dir ? 64 : 0) + c) * T_LEN;
    double y1 = 0.0, y2 = 0.0;
    if (dir == 0) {
        for (int tb = 0; tb < T_LEN; tb += 32) {
            float4 fb[8];
            #pragma unroll
            for (int jj = 0; jj < 32; ++jj) {
                double y = fma(-a1, y1,
                               fma(-a2, y2, b0 * (double)xb[tb + jj]));
                y2 = y1; y1 = y;
                (&fb[jj >> 2].x)[jj & 3] = (float)y;
            }
            #pragma unroll
            for (int i = 0; i < 8; ++i)
                *(float4*)&rowp[tb + 4 * i] = fb[i];
        }
    } else {
        for (int tb = 0; tb < T_LEN; tb += 32) {
            float4 fb[8];
            #pragma unroll
            for (int jj = 0; jj < 32; ++jj) {
                double y = fma(-a1, y1,
                               fma(-a2, y2,
                                   b0 * (double)xb[T_LEN - 1 - tb - jj]));
                y2 = y1; y1 = y;
                (&fb[(31 - jj) >> 2].x)[(31 - jj) & 3] = (float)y;
            }
            const int cb = T_LEN - 32 - tb;
            #pragma unroll
            for (int i = 0; i < 8; ++i)
                *(float4*)&rowp[cb + 4 * i] = fb[i];
        }
    }
}

// Host-side constant computation (deterministic; runs at capture/validate).
static void make_coeffs(Coeffs& cf) {
    const double l10 = log(10.0), l100 = log(100.0);
    for (int c = 0; c < NCH; ++c) {
        double lf = (c == 63) ? l100 : l10 + (double)c * ((l100 - l10) / 63.0);
        double f  = exp(lf);
        double r  = (c == 63) ? 0.99999
                              : 0.9999 + (double)c * ((0.99999 - 0.9999) / 63.0);
        double th = (2.0 * M_PI) * f / 24000.0;
        double a1 = (-2.0 * r) * cos(th), a2 = r * r, b0 = (1.0 - r) * 0.5;
        double pj1 = 1.0, pj2 = 0.0, pj3 = 0.0;   // p[-1]=1, p[-2]=0
        for (int j = 0; j < LCH; ++j) {
            double p = fma(-a1, pj1, -a2 * pj2);
            pj3 = pj2; pj2 = pj1; pj1 = p;
        }
        cf.a1[c] = a1;  cf.a2[c] = a2;  cf.b0[c] = b0;
        cf.A00[c] = pj1;  cf.A01[c] = -a2 * pj2;
        cf.A10[c] = pj2;  cf.A11[c] = -a2 * pj3;
    }
}

extern "C" void kernel_launch(void* const* d_in, const int* in_sizes, int n_in,
                              void* d_out, int out_size, void* d_ws, size_t ws_size,
                              hipStream_t stream) {
    const float* x = (const float*)d_in[0];
    float* out = (float*)d_out;

    Coeffs cf;
    make_coeffs(cf);

    if (d_ws != nullptr && ws_size >= WS_FULL) {
        double2* stEnd = (double2*)d_ws;
        double2* stEntry = stEnd + ST_D2;
        iir_endstates<<<NBLK, 64, 0, stream>>>(x, cf, stEnd);
        iir_entries<<<NSEQ, 64, 0, stream>>>(cf, stEnd, stEntry);
        iir_output<<<NBLK, 64, 0, stream>>>(x, cf, stEntry, out);
    } else if (d_ws != nullptr && ws_size >= WS_MID) {
        double2* stEnd = (double2*)d_ws;
        iir_endstates<<<NBLK, 64, 0, stream>>>(x, cf, stEnd);
        iir_output_scan<<<NBLK, 64, 0, stream>>>(x, cf, stEnd, out);
    } else {
        iir_direct<<<NSEQ, 64, 0, stream>>>(x, cf, out);
    }
}